// Round 2
// baseline (367.775 us; speedup 1.0000x reference)
//
#include <hip/hip_runtime.h>
#include <hip/hip_bf16.h>

#define SEQ 2048
#define LDQKV 6144

typedef __attribute__((ext_vector_type(8))) __bf16 bf16x8;
typedef __attribute__((ext_vector_type(4))) __bf16 bf16x4;
typedef __attribute__((ext_vector_type(4))) float f32x4;

__device__ __forceinline__ void gload_lds16(const void* g, void* l) {
  __builtin_amdgcn_global_load_lds((__attribute__((address_space(1))) void*)(g),
                                   (__attribute__((address_space(3))) void*)(l), 16, 0, 0);
}

// ---------------- f32 -> bf16 conversion (vectorized) ----------------
__global__ __launch_bounds__(256) void cvt4k(const float* __restrict__ in,
                                             __bf16* __restrict__ out, long n) {
  long i = ((long)blockIdx.x * 256 + threadIdx.x) * 4;
  if (i >= n) return;
  f32x4 v = *(const f32x4*)(in + i);
  bf16x4 o;
  #pragma unroll
  for (int j = 0; j < 4; ++j) o[j] = (__bf16)v[j];
  *(bf16x4*)(out + i) = o;
}

// ---------------- RoPE cos/sin table: tab[0..S*64) = cos, then sin ----------------
// Reference quantizes inv_freq through fp16:
//   exponent = float16(j/64)           (exact in fp16)
//   inv_freq = f32( f16(1.0 / f16(10000.0 ** exponent)) )
// Replicate that chain exactly; mismatch here is worth ~1 rad of phase at m=2047.
__global__ __launch_bounds__(256) void rope_tab_k(const int* __restrict__ pos,
                                                  float* __restrict__ tab) {
  int i = blockIdx.x * 256 + threadIdx.x;   // SEQ*64 threads
  int s = i >> 6, j = i & 63;
  float p = (float)pos[s];
  float pw = powf(10000.0f, (float)j * (1.0f / 64.0f));
  _Float16 ph = (_Float16)pw;               // fp16 round of the pow
  _Float16 ivh = (_Float16)(1.0f / (float)ph);  // fp16 round of the reciprocal
  float freq = (float)ivh;
  float th = p * freq;
  tab[i] = cosf(th);
  tab[SEQ * 64 + i] = sinf(th);
}

// ---------------- RoPE applied in-place to Q (32 heads) and K (8 heads) ----------------
__global__ __launch_bounds__(256) void rope_apply_k(__bf16* __restrict__ qkv,
                                                    const float* __restrict__ tab) {
  int i = blockIdx.x * 256 + threadIdx.x;   // SEQ*40*8 threads
  int dc = i & 7;
  int ht = (i >> 3) % 40;
  int s = i / 320;
  long col = (ht < 32) ? (long)ht * 128 : (long)4096 + (long)(ht - 32) * 128;
  __bf16* p = qkv + (long)s * LDQKV + col + dc * 8;
  bf16x8 lo = *(bf16x8*)p;          // x[d], d in [dc*8, dc*8+8) of lower half
  bf16x8 hi = *(bf16x8*)(p + 64);   // x[d+64]
  const float* tc = tab + (long)s * 64 + dc * 8;
  const float* ts = tc + SEQ * 64;
  bf16x8 lo2, hi2;
  #pragma unroll
  for (int e = 0; e < 8; ++e) {
    float c = tc[e], sn = ts[e];
    float lv = (float)lo[e], hv = (float)hi[e];
    lo2[e] = (__bf16)(lv * c - hv * sn);   // x*cos - x_hi*sin
    hi2[e] = (__bf16)(hv * c + lv * sn);   // x_hi*cos + x_lo*sin
  }
  *(bf16x8*)p = lo2;
  *(bf16x8*)(p + 64) = hi2;
}

// ---------------- NT GEMM: C[M][N] = A[M][K] * B[N][K]^T  (bf16 in, f32 acc) ----------------
// 128x128 tile, BK=64, 4 waves (2x2) of 64x64, 16x16x32 bf16 MFMA.
// LDS linear-dest global_load_lds with pre-swizzled source; reads XOR-swizzled.
template <bool OUT_BF16>
__global__ __launch_bounds__(256) void gemm_nt(const __bf16* __restrict__ A,
                                               const __bf16* __restrict__ B,
                                               void* __restrict__ C,
                                               int K, int ldc) {
  __shared__ __align__(16) __bf16 Al[8192];   // [128][64] swizzled
  __shared__ __align__(16) __bf16 Bl[8192];
  const int tid = threadIdx.x;
  const int wave = tid >> 6, lane = tid & 63;
  const int l15 = lane & 15, l4 = lane >> 4;
  const int brow = blockIdx.x * 128, bcol = blockIdx.y * 128;
  const int wm = wave >> 1, wn = wave & 1;

  f32x4 acc[4][4] = {};

  for (int k0 = 0; k0 < K; k0 += 64) {
    __syncthreads();
    #pragma unroll
    for (int i = 0; i < 4; ++i) {
      int fo = i * 2048 + wave * 512 + lane * 8;   // flat elem offset (linear LDS dest)
      int r = fo >> 6, c = fo & 63;
      int cs = c ^ ((r & 7) << 3);                 // inverse-swizzled global col
      gload_lds16(A + (long)(brow + r) * K + k0 + cs, &Al[i * 2048 + wave * 512]);
      gload_lds16(B + (long)(bcol + r) * K + k0 + cs, &Bl[i * 2048 + wave * 512]);
    }
    __syncthreads();
    #pragma unroll
    for (int ks = 0; ks < 2; ++ks) {
      bf16x8 af[4], bfr[4];
      #pragma unroll
      for (int mi = 0; mi < 4; ++mi) {
        int r = wm * 64 + mi * 16 + l15;
        int c = ks * 32 + l4 * 8;
        af[mi] = *(const bf16x8*)&Al[r * 64 + (c ^ ((r & 7) << 3))];
      }
      #pragma unroll
      for (int ni = 0; ni < 4; ++ni) {
        int r = wn * 64 + ni * 16 + l15;
        int c = ks * 32 + l4 * 8;
        bfr[ni] = *(const bf16x8*)&Bl[r * 64 + (c ^ ((r & 7) << 3))];
      }
      #pragma unroll
      for (int mi = 0; mi < 4; ++mi)
        #pragma unroll
        for (int ni = 0; ni < 4; ++ni)
          acc[mi][ni] = __builtin_amdgcn_mfma_f32_16x16x32_bf16(af[mi], bfr[ni], acc[mi][ni], 0, 0, 0);
    }
  }
  #pragma unroll
  for (int mi = 0; mi < 4; ++mi)
    #pragma unroll
    for (int ni = 0; ni < 4; ++ni)
      #pragma unroll
      for (int j = 0; j < 4; ++j) {
        long rr = brow + wm * 64 + mi * 16 + l4 * 4 + j;   // D row = (lane>>4)*4+reg
        long cc = bcol + wn * 64 + ni * 16 + l15;          // D col = lane&15
        float v = acc[mi][ni][j];
        if (OUT_BF16) ((__bf16*)C)[rr * ldc + cc] = (__bf16)v;
        else          ((float*)C)[rr * ldc + cc] = v;
      }
}

// ---------------- flash attention (causal, GQA 4:1) ----------------
// One block = one (head, 64-row q-tile). 4 waves x 16 q-rows. KVBLK=64.
__global__ __launch_bounds__(256) void flash_k(const __bf16* __restrict__ qkv,
                                               __bf16* __restrict__ ctx) {
  __shared__ __align__(16) __bf16 Kl[8192];      // [64][128] swizzled
  __shared__ __align__(16) __bf16 Vt[128 * 72];  // [d][kv] rows padded to 72 elems (144B)
  __shared__ __align__(16) __bf16 Pl[4][1024];   // per-wave [16][64] swizzled

  const int bid = blockIdx.x;
  const int h = bid & 31;
  const int qt = 31 - (bid >> 5);    // heavy tiles first
  const int kvh = h >> 2;
  const int q0 = qt * 64;
  const int tid = threadIdx.x, wave = tid >> 6, lane = tid & 63;
  const int l15 = lane & 15, l4 = lane >> 4;
  const int d2 = tid & 63, grp = tid >> 6;

  const __bf16* Qp = qkv + (long)h * 128;
  const __bf16* Kp = qkv + 4096 + (long)kvh * 128;
  const __bf16* Vp = qkv + 5120 + (long)kvh * 128;

  // Q fragments held in registers for the whole kv loop
  bf16x8 aq[4];
  {
    long qr = q0 + wave * 16 + l15;
    #pragma unroll
    for (int ks = 0; ks < 4; ++ks)
      aq[ks] = *(const bf16x8*)(Qp + qr * LDQKV + ks * 32 + l4 * 8);
  }
  f32x4 accO[8] = {};
  float mrow[4], lsum[4];
  #pragma unroll
  for (int j = 0; j < 4; ++j) { mrow[j] = -3.0e30f; lsum[j] = 0.f; }
  const float scale = 0.08838834764831845f;   // 1/sqrt(128)

  for (int kv0 = 0; kv0 <= q0; kv0 += 64) {
    __syncthreads();
    // stage K tile (swizzled via pre-swizzled source, linear LDS dest)
    #pragma unroll
    for (int i = 0; i < 4; ++i) {
      int fo = i * 2048 + wave * 512 + lane * 8;
      int r = fo >> 7, c = fo & 127;
      int cs = c ^ ((r & 7) << 3);
      gload_lds16(Kp + (long)(kv0 + r) * LDQKV + cs, &Kl[i * 2048 + wave * 512]);
    }
    // stage V transposed: coalesced dword loads (2 bf16 along d), b128 LDS writes
    unsigned int vv[2][8];
    #pragma unroll
    for (int rep = 0; rep < 2; ++rep) {
      int cch = grp * 2 + rep;
      #pragma unroll
      for (int i = 0; i < 8; ++i)
        vv[rep][i] = *(const unsigned int*)(Vp + (long)(kv0 + cch * 8 + i) * LDQKV + 2 * d2);
    }
    #pragma unroll
    for (int rep = 0; rep < 2; ++rep) {
      int cch = grp * 2 + rep;
      #pragma unroll
      for (int half = 0; half < 2; ++half) {
        bf16x8 w;
        #pragma unroll
        for (int i = 0; i < 8; ++i)
          w[i] = __builtin_bit_cast(__bf16, (unsigned short)(vv[rep][i] >> (16 * half)));
        *(bf16x8*)&Vt[(2 * d2 + half) * 72 + cch * 8] = w;
      }
    }
    __syncthreads();

    // QK^T : S[16q][64kv] per wave (4 col-tiles of 16)
    f32x4 s[4];
    #pragma unroll
    for (int t = 0; t < 4; ++t) s[t] = f32x4{0.f, 0.f, 0.f, 0.f};
    #pragma unroll
    for (int t = 0; t < 4; ++t) {
      #pragma unroll
      for (int ks = 0; ks < 4; ++ks) {
        int r = t * 16 + l15;
        int c = ks * 32 + l4 * 8;
        bf16x8 bk = *(const bf16x8*)&Kl[r * 128 + (c ^ ((r & 7) << 3))];
        s[t] = __builtin_amdgcn_mfma_f32_16x16x32_bf16(aq[ks], bk, s[t], 0, 0, 0);
      }
    }
    // scale + causal mask (only possible on the diagonal step kv0==q0)
    const bool lastStep = (kv0 == q0);
    #pragma unroll
    for (int t = 0; t < 4; ++t)
      #pragma unroll
      for (int j = 0; j < 4; ++j) {
        float v = s[t][j] * scale;
        if (lastStep) {
          int qg = wave * 16 + l4 * 4 + j;   // local q row
          int kg = t * 16 + l15;             // local kv col
          if (kg > qg) v = -3.0e30f;
        }
        s[t][j] = v;
      }
    // online softmax (row stats across the 16 lanes of each l4-group)
    float pout[4][4];
    #pragma unroll
    for (int j = 0; j < 4; ++j) {
      float vm = fmaxf(fmaxf(s[0][j], s[1][j]), fmaxf(s[2][j], s[3][j]));
      vm = fmaxf(vm, __shfl_xor(vm, 1, 16));
      vm = fmaxf(vm, __shfl_xor(vm, 2, 16));
      vm = fmaxf(vm, __shfl_xor(vm, 4, 16));
      vm = fmaxf(vm, __shfl_xor(vm, 8, 16));
      float nm = fmaxf(mrow[j], vm);
      float sc = exp2f((mrow[j] - nm) * 1.4426950408889634f);
      mrow[j] = nm;
      float ps = 0.f;
      #pragma unroll
      for (int t = 0; t < 4; ++t) {
        float p = exp2f((s[t][j] - nm) * 1.4426950408889634f);
        pout[t][j] = p; ps += p;
      }
      lsum[j] = lsum[j] * sc + ps;
      #pragma unroll
      for (int dt = 0; dt < 8; ++dt) accO[dt][j] *= sc;
    }
    // P -> per-wave LDS (swizzled), then redistribute as MFMA A-operand
    #pragma unroll
    for (int t = 0; t < 4; ++t)
      #pragma unroll
      for (int j = 0; j < 4; ++j) {
        int r = l4 * 4 + j;
        int c = t * 16 + l15;
        Pl[wave][r * 64 + (c ^ ((r & 7) << 3))] = (__bf16)pout[t][j];
      }
    asm volatile("s_waitcnt lgkmcnt(0)" ::: "memory");
    __builtin_amdgcn_sched_barrier(0);
    bf16x8 ap[2];
    #pragma unroll
    for (int ks2 = 0; ks2 < 2; ++ks2) {
      int c = ks2 * 32 + l4 * 8;
      ap[ks2] = *(const bf16x8*)&Pl[wave][l15 * 64 + (c ^ ((l15 & 7) << 3))];
    }
    // PV: accO[dt] over 8 d-tiles
    #pragma unroll
    for (int dt = 0; dt < 8; ++dt) {
      #pragma unroll
      for (int ks2 = 0; ks2 < 2; ++ks2) {
        int d = dt * 16 + l15;
        int c = ks2 * 32 + l4 * 8;
        bf16x8 bv = *(const bf16x8*)&Vt[d * 72 + c];
        accO[dt] = __builtin_amdgcn_mfma_f32_16x16x32_bf16(ap[ks2], bv, accO[dt], 0, 0, 0);
      }
    }
  }
  // finalize: divide by row sums, write ctx[s][h*128+d] bf16
  float rls[4];
  #pragma unroll
  for (int j = 0; j < 4; ++j) {
    float ls = lsum[j];
    ls += __shfl_xor(ls, 1, 16);
    ls += __shfl_xor(ls, 2, 16);
    ls += __shfl_xor(ls, 4, 16);
    ls += __shfl_xor(ls, 8, 16);
    rls[j] = 1.f / ls;
  }
  #pragma unroll
  for (int dt = 0; dt < 8; ++dt)
    #pragma unroll
    for (int j = 0; j < 4; ++j) {
      long qr = q0 + wave * 16 + l4 * 4 + j;
      long cc = (long)h * 128 + dt * 16 + l15;
      ctx[qr * 4096 + cc] = (__bf16)(accO[dt][j] * rls[j]);
    }
}

// ---------------- launch ----------------
extern "C" void kernel_launch(void* const* d_in, const int* in_sizes, int n_in,
                              void* d_out, int out_size, void* d_ws, size_t ws_size,
                              hipStream_t stream) {
  const float* hs  = (const float*)d_in[0];
  const int*   pos = (const int*)d_in[2];
  const float* Wq  = (const float*)d_in[3];
  const float* Wk  = (const float*)d_in[4];
  const float* Wv  = (const float*)d_in[5];
  const float* Wo  = (const float*)d_in[6];
  char* ws = (char*)d_ws;
  __bf16* hsb  = (__bf16*)(ws + 0L);           // 16,777,216 B
  __bf16* wqkv = (__bf16*)(ws + 16777216L);    // 50,331,648 B
  __bf16* wob  = (__bf16*)(ws + 67108864L);    // 33,554,432 B
  __bf16* qkvb = (__bf16*)(ws + 100663296L);   // 25,165,824 B  [2048][6144]
  float*  tab  = (float*)(ws + 125829120L);    //  1,048,576 B
  __bf16* ctx  = (__bf16*)(ws + 126877696L);   // 16,777,216 B  [2048][4096]

  cvt4k<<<8192, 256, 0, stream>>>(hs, hsb, 8388608L);
  cvt4k<<<16384, 256, 0, stream>>>(Wq, wqkv, 16777216L);
  cvt4k<<<4096, 256, 0, stream>>>(Wk, wqkv + 16777216L, 4194304L);
  cvt4k<<<4096, 256, 0, stream>>>(Wv, wqkv + 20971520L, 4194304L);
  cvt4k<<<16384, 256, 0, stream>>>(Wo, wob, 16777216L);
  rope_tab_k<<<512, 256, 0, stream>>>(pos, tab);

  dim3 g1(16, 48);   // M/128 x 6144/128
  gemm_nt<true><<<g1, 256, 0, stream>>>(hsb, wqkv, qkvb, 4096, 6144);

  rope_apply_k<<<2560, 256, 0, stream>>>(qkvb, tab);

  flash_k<<<1024, 256, 0, stream>>>(qkvb, ctx);

  dim3 g2(16, 32);   // M/128 x 4096/128
  gemm_nt<false><<<g2, 256, 0, stream>>>(ctx, wob, d_out, 4096, 4096);
}